// Round 1
// baseline (7357.541 us; speedup 1.0000x reference)
//
#include <hip/hip_runtime.h>

#define NN 100000
#define NE 600000
#define EMB 128

__device__ __forceinline__ float4 ld4(const float* p) { return *(const float4*)p; }

// -------------------- node embedding init: h = emb1[x0] + emb2[x1] --------------------
__global__ __launch_bounds__(256) void node_init_kernel(
    const int* __restrict__ x, const float* __restrict__ emb1,
    const float* __restrict__ emb2, float* __restrict__ h) {
  int tid = blockIdx.x * blockDim.x + threadIdx.x;
  int n = tid >> 5;
  if (n >= NN) return;
  int f = (tid & 31) << 2;
  int x0 = x[2 * n], x1 = x[2 * n + 1];
  x0 = min(max(x0, 0), 118);
  x1 = min(max(x1, 0), 2);   // CRITICAL: x[:,1] sampled 0..118, must clip to NUM_CHIR-1
  float4 a = ld4(emb1 + (size_t)x0 * EMB + f);
  float4 b = ld4(emb2 + (size_t)x1 * EMB + f);
  float4 r;
  r.x = a.x + b.x; r.y = a.y + b.y; r.z = a.z + b.z; r.w = a.w + b.w;
  *(float4*)(h + (size_t)n * EMB + f) = r;
}

// -------------------- message passing: agg[dst] += relu(h[src] + e) --------------------
// 32 threads per edge (incl. NN self loops), 4 feats each (float4), f32 atomics into agg.
__global__ __launch_bounds__(256) void msg_kernel(
    const float* __restrict__ h, const int* __restrict__ ei,
    const int* __restrict__ ea, const float* __restrict__ ee1,
    const float* __restrict__ ee2, float* __restrict__ agg) {
  int tid = blockIdx.x * blockDim.x + threadIdx.x;
  int e = tid >> 5;
  if (e >= NE + NN) return;
  int f = (tid & 31) << 2;
  int src, dst, a0, a1;
  if (e < NE) {
    src = ei[e];
    dst = ei[NE + e];
    a0 = ea[2 * e];
    a1 = ea[2 * e + 1];
    a0 = min(max(a0, 0), 4);
    a1 = min(max(a1, 0), 2);
  } else {           // self loop: src=dst=node, bond type 0 / dir 0
    src = e - NE; dst = src; a0 = 0; a1 = 0;
  }
  float4 e1 = ld4(ee1 + (size_t)a0 * EMB + f);
  float4 e2 = ld4(ee2 + (size_t)a1 * EMB + f);
  float4 hv = ld4(h + (size_t)src * EMB + f);
  float mx = fmaxf(hv.x + e1.x + e2.x, 0.f);
  float my = fmaxf(hv.y + e1.y + e2.y, 0.f);
  float mz = fmaxf(hv.z + e1.z + e2.z, 0.f);
  float mw = fmaxf(hv.w + e1.w + e2.w, 0.f);
  float* ap = agg + (size_t)dst * EMB + f;
  atomicAdd(ap + 0, mx);
  atomicAdd(ap + 1, my);
  atomicAdd(ap + 2, mz);
  atomicAdd(ap + 3, mw);
}

// -------------------- tiled f32 GEMM: C[M,NC] = act(A[M,K] @ B[K,NC] + bias) --------------------
// 64x64 output tile, 256 threads, 4x4 register blocking, BK=64.
// FUSEA: A row = (1+eps)*h + agg  (GIN combine fused into the A-tile load).
template <int K, int NC, bool FUSEA, bool RELU>
__global__ __launch_bounds__(256) void gemm_kernel(
    const float* __restrict__ A, const float* __restrict__ A2,
    const float* __restrict__ epsp, const float* __restrict__ B,
    const float* __restrict__ bias, float* __restrict__ C) {
  __shared__ float As[64][65];   // +1 pad: As[r][k] reads are conflict-free broadcast
  __shared__ float Bs[64][64];   // Bs[k][c] float4 reads: 2-way (free on CDNA4)
  const int t = threadIdx.x;
  const int tx = t & 15, ty = t >> 4;
  const int m0 = blockIdx.y * 64;
  const int c0 = blockIdx.x * 64;
  const float eps1 = FUSEA ? (1.0f + *epsp) : 0.0f;
  float acc[4][4] = {};

  for (int kt = 0; kt < K; kt += 64) {
    // --- stage A tile (rows m0..m0+63, k kt..kt+63) ---
    {
      int kq = (t & 15) << 2;
      int r0 = t >> 4;
#pragma unroll
      for (int p = 0; p < 4; ++p) {
        int r = r0 + p * 16;
        int row = m0 + r;
        float4 v;
        if (row < NN) {
          if (FUSEA) {
            float4 hv = ld4(A + (size_t)row * K + kt + kq);
            float4 av = ld4(A2 + (size_t)row * K + kt + kq);
            v.x = eps1 * hv.x + av.x;
            v.y = eps1 * hv.y + av.y;
            v.z = eps1 * hv.z + av.z;
            v.w = eps1 * hv.w + av.w;
          } else {
            v = ld4(A + (size_t)row * K + kt + kq);
          }
        } else {
          v = make_float4(0.f, 0.f, 0.f, 0.f);
        }
        As[r][kq + 0] = v.x;
        As[r][kq + 1] = v.y;
        As[r][kq + 2] = v.z;
        As[r][kq + 3] = v.w;
      }
    }
    // --- stage B tile (k kt..kt+63, cols c0..c0+63) ---
    {
      int c = (t & 15) << 2;
      int k0 = t >> 4;
#pragma unroll
      for (int p = 0; p < 4; ++p) {
        int k = k0 + p * 16;
        float4 v = ld4(B + (size_t)(kt + k) * NC + c0 + c);
        *(float4*)&Bs[k][c] = v;
      }
    }
    __syncthreads();
#pragma unroll 8
    for (int k = 0; k < 64; ++k) {
      float a0 = As[ty * 4 + 0][k];
      float a1 = As[ty * 4 + 1][k];
      float a2 = As[ty * 4 + 2][k];
      float a3 = As[ty * 4 + 3][k];
      float4 b = *(float4*)&Bs[k][tx * 4];
      acc[0][0] += a0 * b.x; acc[0][1] += a0 * b.y; acc[0][2] += a0 * b.z; acc[0][3] += a0 * b.w;
      acc[1][0] += a1 * b.x; acc[1][1] += a1 * b.y; acc[1][2] += a1 * b.z; acc[1][3] += a1 * b.w;
      acc[2][0] += a2 * b.x; acc[2][1] += a2 * b.y; acc[2][2] += a2 * b.z; acc[2][3] += a2 * b.w;
      acc[3][0] += a3 * b.x; acc[3][1] += a3 * b.y; acc[3][2] += a3 * b.z; acc[3][3] += a3 * b.w;
    }
    __syncthreads();
  }

  float4 bv = ld4(bias + c0 + tx * 4);
#pragma unroll
  for (int ri = 0; ri < 4; ++ri) {
    int row = m0 + ty * 4 + ri;
    if (row >= NN) continue;
    float4 o;
    o.x = acc[ri][0] + bv.x;
    o.y = acc[ri][1] + bv.y;
    o.z = acc[ri][2] + bv.z;
    o.w = acc[ri][3] + bv.w;
    if (RELU) {
      o.x = fmaxf(o.x, 0.f); o.y = fmaxf(o.y, 0.f);
      o.z = fmaxf(o.z, 0.f); o.w = fmaxf(o.w, 0.f);
    }
    *(float4*)(C + (size_t)row * NC + c0 + tx * 4) = o;
  }
}

// -------------------- BatchNorm: reduce, stats, apply --------------------
__global__ __launch_bounds__(256) void bn_reduce_kernel(
    const float* __restrict__ hp, float* __restrict__ sums) {
  int f = threadIdx.x & 127;
  int half = threadIdx.x >> 7;
  float s = 0.f, s2 = 0.f;
  for (int n = blockIdx.x * 2 + half; n < NN; n += gridDim.x * 2) {
    float v = hp[(size_t)n * EMB + f];
    s += v;
    s2 += v * v;
  }
  atomicAdd(&sums[f], s);
  atomicAdd(&sums[128 + f], s2);
}

__global__ void bn_stats_kernel(const float* __restrict__ sums,
                                const float* __restrict__ gamma,
                                const float* __restrict__ beta,
                                float* __restrict__ ss) {
  int f = threadIdx.x;  // 128 threads
  float mean = sums[f] * (1.0f / NN);
  float var = sums[128 + f] * (1.0f / NN) - mean * mean;  // biased variance
  float sc = gamma[f] * rsqrtf(var + 1e-5f);
  ss[f] = sc;
  ss[128 + f] = beta[f] - mean * sc;
}

template <bool RELU>
__global__ __launch_bounds__(256) void bn_apply_kernel(
    const float* __restrict__ hp, const float* __restrict__ ss,
    float* __restrict__ dst) {
  int tid = blockIdx.x * blockDim.x + threadIdx.x;
  int n = tid >> 5;
  if (n >= NN) return;
  int f = (tid & 31) << 2;
  float4 v = ld4(hp + (size_t)n * EMB + f);
  float4 sc = ld4(ss + f);
  float4 sh = ld4(ss + 128 + f);
  v.x = v.x * sc.x + sh.x;
  v.y = v.y * sc.y + sh.y;
  v.z = v.z * sc.z + sh.z;
  v.w = v.w * sc.w + sh.w;
  if (RELU) {
    v.x = fmaxf(v.x, 0.f); v.y = fmaxf(v.y, 0.f);
    v.z = fmaxf(v.z, 0.f); v.w = fmaxf(v.w, 0.f);
  }
  *(float4*)(dst + (size_t)n * EMB + f) = v;
}

// -------------------- launch --------------------
extern "C" void kernel_launch(void* const* d_in, const int* in_sizes, int n_in,
                              void* d_out, int out_size, void* d_ws, size_t ws_size,
                              hipStream_t stream) {
  const int* x = (const int*)d_in[0];
  const int* ei = (const int*)d_in[1];       // [2, NE]
  const int* ea = (const int*)d_in[2];       // [NE, 2]
  const float* x_emb1 = (const float*)d_in[3];
  const float* x_emb2 = (const float*)d_in[4];
  const float* ee1 = (const float*)d_in[5];  // [5][5][128]
  const float* ee2 = (const float*)d_in[6];  // [5][3][128]
  const float* W1 = (const float*)d_in[7];   // [5][128][256]
  const float* b1 = (const float*)d_in[8];   // [5][256]
  const float* W2 = (const float*)d_in[9];   // [5][256][128]
  const float* b2 = (const float*)d_in[10];  // [5][128]
  const float* eps = (const float*)d_in[11]; // [5]
  const float* gamma = (const float*)d_in[12];
  const float* beta = (const float*)d_in[13];
  float* out = (float*)d_out;

  // workspace: hbuf(51.2MB) | agg/hpre(51.2MB) | hmid(102.4MB) | sums(1KB) | ss(1KB)
  float* hbuf = (float*)d_ws;
  float* agg = hbuf + (size_t)NN * EMB;
  float* hmid = agg + (size_t)NN * EMB;
  float* sums = hmid + (size_t)NN * 256;
  float* ss = sums + 256;

  node_init_kernel<<<(NN * 32 + 255) / 256, 256, 0, stream>>>(x, x_emb1, x_emb2, hbuf);

  for (int i = 0; i < 5; ++i) {
    hipMemsetAsync(agg, 0, (size_t)NN * EMB * sizeof(float), stream);
    hipMemsetAsync(sums, 0, 256 * sizeof(float), stream);

    msg_kernel<<<((NE + NN) * 32 + 255) / 256, 256, 0, stream>>>(
        hbuf, ei, ea, ee1 + (size_t)i * 5 * EMB, ee2 + (size_t)i * 3 * EMB, agg);

    dim3 g1(4, (NN + 63) / 64);
    gemm_kernel<128, 256, true, true><<<g1, 256, 0, stream>>>(
        hbuf, agg, eps + i, W1 + (size_t)i * 128 * 256, b1 + (size_t)i * 256, hmid);

    dim3 g2(2, (NN + 63) / 64);
    gemm_kernel<256, 128, false, false><<<g2, 256, 0, stream>>>(
        hmid, nullptr, nullptr, W2 + (size_t)i * 256 * 128, b2 + (size_t)i * 128,
        agg /* hpre aliases agg: agg already consumed by gemm1 */);

    bn_reduce_kernel<<<512, 256, 0, stream>>>(agg, sums);
    bn_stats_kernel<<<1, 128, 0, stream>>>(sums, gamma + (size_t)i * EMB,
                                           beta + (size_t)i * EMB, ss);
    if (i < 4)
      bn_apply_kernel<true><<<(NN * 32 + 255) / 256, 256, 0, stream>>>(agg, ss, hbuf);
    else
      bn_apply_kernel<false><<<(NN * 32 + 255) / 256, 256, 0, stream>>>(agg, ss, out);
  }
}

// Round 2
// 1839.187 us; speedup vs baseline: 4.0004x; 4.0004x over previous
//
#include <hip/hip_runtime.h>

#define NN 100000
#define NE 600000
#define EMB 128

__device__ __forceinline__ float4 ld4(const float* p) { return *(const float4*)p; }

// -------------------- node embedding init: h = emb1[x0] + emb2[x1] --------------------
__global__ __launch_bounds__(256) void node_init_kernel(
    const int* __restrict__ x, const float* __restrict__ emb1,
    const float* __restrict__ emb2, float* __restrict__ h) {
  int tid = blockIdx.x * blockDim.x + threadIdx.x;
  int n = tid >> 5;
  if (n >= NN) return;
  int f = (tid & 31) << 2;
  int x0 = x[2 * n], x1 = x[2 * n + 1];
  x0 = min(max(x0, 0), 118);
  x1 = min(max(x1, 0), 2);   // CRITICAL: x[:,1] sampled 0..118, must clip to NUM_CHIR-1
  float4 a = ld4(emb1 + (size_t)x0 * EMB + f);
  float4 b = ld4(emb2 + (size_t)x1 * EMB + f);
  float4 r;
  r.x = a.x + b.x; r.y = a.y + b.y; r.z = a.z + b.z; r.w = a.w + b.w;
  *(float4*)(h + (size_t)n * EMB + f) = r;
}

// -------------------- CSR build --------------------
__global__ __launch_bounds__(256) void hist_kernel(const int* __restrict__ ei,
                                                   int* __restrict__ deg) {
  int e = blockIdx.x * blockDim.x + threadIdx.x;
  if (e >= NE) return;
  atomicAdd(&deg[ei[NE + e]], 1);
}

// block scan: 256 threads x 4 elems = 1024 elems/block
__global__ __launch_bounds__(256) void scan1_kernel(const int* __restrict__ deg,
                                                    int* __restrict__ off,
                                                    int* __restrict__ bsum) {
  __shared__ int s[256];
  int t = threadIdx.x;
  int base = blockIdx.x * 1024 + t * 4;
  int v[4];
#pragma unroll
  for (int j = 0; j < 4; ++j) {
    int idx = base + j;
    v[j] = (idx < NN) ? deg[idx] : 0;
  }
  int tsum = v[0] + v[1] + v[2] + v[3];
  s[t] = tsum;
  __syncthreads();
  for (int d = 1; d < 256; d <<= 1) {
    int add = (t >= d) ? s[t - d] : 0;
    __syncthreads();
    s[t] += add;
    __syncthreads();
  }
  int run = s[t] - tsum;  // exclusive prefix of this thread
#pragma unroll
  for (int j = 0; j < 4; ++j) {
    int idx = base + j;
    if (idx < NN) off[idx] = run;
    run += v[j];
  }
  if (t == 255) bsum[blockIdx.x] = s[255];
}

__global__ void scan2_kernel(int* __restrict__ bsum, int* __restrict__ off, int nb) {
  if (threadIdx.x == 0) {
    int run = 0;
    for (int b = 0; b < nb; ++b) {
      int v = bsum[b];
      bsum[b] = run;
      run += v;
    }
    off[NN] = run;
  }
}

__global__ __launch_bounds__(256) void scan3_kernel(int* __restrict__ off,
                                                    const int* __restrict__ bsum) {
  int idx = blockIdx.x * blockDim.x + threadIdx.x;
  if (idx < NN) off[idx] += bsum[idx >> 10];
}

__global__ __launch_bounds__(256) void scatter_kernel(
    const int* __restrict__ ei, const int* __restrict__ ea,
    const int* __restrict__ off, int* __restrict__ cnt, int* __restrict__ csr) {
  int e = blockIdx.x * blockDim.x + threadIdx.x;
  if (e >= NE) return;
  int d = ei[NE + e];
  int s = ei[e];
  int a0 = min(max(ea[2 * e], 0), 4);
  int a1 = min(max(ea[2 * e + 1], 0), 2);
  int code = a0 * 3 + a1;  // [0,14]
  int r = atomicAdd(&cnt[d], 1);
  csr[off[d] + r] = s | (code << 20);
}

// combos[l][code][f] = ee1[l][code/3][f] + ee2[l][code%3][f]; 5*15*128 elems
__global__ __launch_bounds__(256) void combo_kernel(const float* __restrict__ ee1,
                                                    const float* __restrict__ ee2,
                                                    float* __restrict__ combos) {
  int idx = blockIdx.x * blockDim.x + threadIdx.x;
  if (idx >= 5 * 15 * 128) return;
  int l = idx / (15 * 128);
  int rem = idx % (15 * 128);
  int code = rem / 128;
  int f = rem % 128;
  combos[idx] = ee1[(l * 5 + code / 3) * 128 + f] + ee2[(l * 3 + code % 3) * 128 + f];
}

// -------------------- aggregation: agg[d] = sum_in relu(h[src]+e) + relu(h[d]+e00) --------------------
// 32 lanes per dst node, float4 per lane. No atomics; one write per agg row.
__global__ __launch_bounds__(256) void gather_agg_kernel(
    const float* __restrict__ h, const int* __restrict__ off,
    const int* __restrict__ csr, const float* __restrict__ combos,
    float* __restrict__ agg) {
  int tid = blockIdx.x * blockDim.x + threadIdx.x;
  int g = tid >> 5;
  if (g >= NN) return;
  int f = (tid & 31) << 2;
  // self loop: code 0
  float4 hv = ld4(h + (size_t)g * EMB + f);
  float4 ev = ld4(combos + f);
  float4 acc;
  acc.x = fmaxf(hv.x + ev.x, 0.f);
  acc.y = fmaxf(hv.y + ev.y, 0.f);
  acc.z = fmaxf(hv.z + ev.z, 0.f);
  acc.w = fmaxf(hv.w + ev.w, 0.f);
  int s0 = off[g], s1 = off[g + 1];
  for (int j = s0; j < s1; ++j) {
    int p = csr[j];
    int src = p & 0xFFFFF;
    int code = p >> 20;
    float4 sv = ld4(h + (size_t)src * EMB + f);
    float4 cv = ld4(combos + (size_t)code * EMB + f);
    acc.x += fmaxf(sv.x + cv.x, 0.f);
    acc.y += fmaxf(sv.y + cv.y, 0.f);
    acc.z += fmaxf(sv.z + cv.z, 0.f);
    acc.w += fmaxf(sv.w + cv.w, 0.f);
  }
  *(float4*)(agg + (size_t)g * EMB + f) = acc;
}

// -------------------- tiled f32 GEMM: C[M,NC] = act(A[M,K] @ B[K,NC] + bias) --------------------
template <int K, int NC, bool FUSEA, bool RELU>
__global__ __launch_bounds__(256) void gemm_kernel(
    const float* __restrict__ A, const float* __restrict__ A2,
    const float* __restrict__ epsp, const float* __restrict__ B,
    const float* __restrict__ bias, float* __restrict__ C) {
  __shared__ float As[64][65];
  __shared__ float Bs[64][64];
  const int t = threadIdx.x;
  const int tx = t & 15, ty = t >> 4;
  const int m0 = blockIdx.y * 64;
  const int c0 = blockIdx.x * 64;
  const float eps1 = FUSEA ? (1.0f + *epsp) : 0.0f;
  float acc[4][4] = {};

  for (int kt = 0; kt < K; kt += 64) {
    {
      int kq = (t & 15) << 2;
      int r0 = t >> 4;
#pragma unroll
      for (int p = 0; p < 4; ++p) {
        int r = r0 + p * 16;
        int row = m0 + r;
        float4 v;
        if (row < NN) {
          if (FUSEA) {
            float4 hv = ld4(A + (size_t)row * K + kt + kq);
            float4 av = ld4(A2 + (size_t)row * K + kt + kq);
            v.x = eps1 * hv.x + av.x;
            v.y = eps1 * hv.y + av.y;
            v.z = eps1 * hv.z + av.z;
            v.w = eps1 * hv.w + av.w;
          } else {
            v = ld4(A + (size_t)row * K + kt + kq);
          }
        } else {
          v = make_float4(0.f, 0.f, 0.f, 0.f);
        }
        As[r][kq + 0] = v.x;
        As[r][kq + 1] = v.y;
        As[r][kq + 2] = v.z;
        As[r][kq + 3] = v.w;
      }
    }
    {
      int c = (t & 15) << 2;
      int k0 = t >> 4;
#pragma unroll
      for (int p = 0; p < 4; ++p) {
        int k = k0 + p * 16;
        float4 v = ld4(B + (size_t)(kt + k) * NC + c0 + c);
        *(float4*)&Bs[k][c] = v;
      }
    }
    __syncthreads();
#pragma unroll 8
    for (int k = 0; k < 64; ++k) {
      float a0 = As[ty * 4 + 0][k];
      float a1 = As[ty * 4 + 1][k];
      float a2 = As[ty * 4 + 2][k];
      float a3 = As[ty * 4 + 3][k];
      float4 b = *(float4*)&Bs[k][tx * 4];
      acc[0][0] += a0 * b.x; acc[0][1] += a0 * b.y; acc[0][2] += a0 * b.z; acc[0][3] += a0 * b.w;
      acc[1][0] += a1 * b.x; acc[1][1] += a1 * b.y; acc[1][2] += a1 * b.z; acc[1][3] += a1 * b.w;
      acc[2][0] += a2 * b.x; acc[2][1] += a2 * b.y; acc[2][2] += a2 * b.z; acc[2][3] += a2 * b.w;
      acc[3][0] += a3 * b.x; acc[3][1] += a3 * b.y; acc[3][2] += a3 * b.z; acc[3][3] += a3 * b.w;
    }
    __syncthreads();
  }

  float4 bv = ld4(bias + c0 + tx * 4);
#pragma unroll
  for (int ri = 0; ri < 4; ++ri) {
    int row = m0 + ty * 4 + ri;
    if (row >= NN) continue;
    float4 o;
    o.x = acc[ri][0] + bv.x;
    o.y = acc[ri][1] + bv.y;
    o.z = acc[ri][2] + bv.z;
    o.w = acc[ri][3] + bv.w;
    if (RELU) {
      o.x = fmaxf(o.x, 0.f); o.y = fmaxf(o.y, 0.f);
      o.z = fmaxf(o.z, 0.f); o.w = fmaxf(o.w, 0.f);
    }
    *(float4*)(C + (size_t)row * NC + c0 + tx * 4) = o;
  }
}

// -------------------- BatchNorm: reduce, stats, apply --------------------
__global__ __launch_bounds__(256) void bn_reduce_kernel(
    const float* __restrict__ hp, float* __restrict__ sums) {
  int f = threadIdx.x & 127;
  int half = threadIdx.x >> 7;
  float s = 0.f, s2 = 0.f;
  for (int n = blockIdx.x * 2 + half; n < NN; n += gridDim.x * 2) {
    float v = hp[(size_t)n * EMB + f];
    s += v;
    s2 += v * v;
  }
  atomicAdd(&sums[f], s);
  atomicAdd(&sums[128 + f], s2);
}

__global__ void bn_stats_kernel(const float* __restrict__ sums,
                                const float* __restrict__ gamma,
                                const float* __restrict__ beta,
                                float* __restrict__ ss) {
  int f = threadIdx.x;  // 128 threads
  float mean = sums[f] * (1.0f / NN);
  float var = sums[128 + f] * (1.0f / NN) - mean * mean;  // biased variance
  float sc = gamma[f] * rsqrtf(var + 1e-5f);
  ss[f] = sc;
  ss[128 + f] = beta[f] - mean * sc;
}

template <bool RELU>
__global__ __launch_bounds__(256) void bn_apply_kernel(
    const float* __restrict__ hp, const float* __restrict__ ss,
    float* __restrict__ dst) {
  int tid = blockIdx.x * blockDim.x + threadIdx.x;
  int n = tid >> 5;
  if (n >= NN) return;
  int f = (tid & 31) << 2;
  float4 v = ld4(hp + (size_t)n * EMB + f);
  float4 sc = ld4(ss + f);
  float4 sh = ld4(ss + 128 + f);
  v.x = v.x * sc.x + sh.x;
  v.y = v.y * sc.y + sh.y;
  v.z = v.z * sc.z + sh.z;
  v.w = v.w * sc.w + sh.w;
  if (RELU) {
    v.x = fmaxf(v.x, 0.f); v.y = fmaxf(v.y, 0.f);
    v.z = fmaxf(v.z, 0.f); v.w = fmaxf(v.w, 0.f);
  }
  *(float4*)(dst + (size_t)n * EMB + f) = v;
}

// -------------------- launch --------------------
extern "C" void kernel_launch(void* const* d_in, const int* in_sizes, int n_in,
                              void* d_out, int out_size, void* d_ws, size_t ws_size,
                              hipStream_t stream) {
  const int* x = (const int*)d_in[0];
  const int* ei = (const int*)d_in[1];       // [2, NE]
  const int* ea = (const int*)d_in[2];       // [NE, 2]
  const float* x_emb1 = (const float*)d_in[3];
  const float* x_emb2 = (const float*)d_in[4];
  const float* ee1 = (const float*)d_in[5];  // [5][5][128]
  const float* ee2 = (const float*)d_in[6];  // [5][3][128]
  const float* W1 = (const float*)d_in[7];   // [5][128][256]
  const float* b1 = (const float*)d_in[8];   // [5][256]
  const float* W2 = (const float*)d_in[9];   // [5][256][128]
  const float* b2 = (const float*)d_in[10];  // [5][128]
  const float* eps = (const float*)d_in[11]; // [5]
  const float* gamma = (const float*)d_in[12];
  const float* beta = (const float*)d_in[13];
  float* out = (float*)d_out;

  // workspace layout
  float* hbuf = (float*)d_ws;                    // NN*128
  float* agg = hbuf + (size_t)NN * EMB;          // NN*128
  float* hmid = agg + (size_t)NN * EMB;          // NN*256
  float* sums = hmid + (size_t)NN * 256;         // 256
  float* ss = sums + 256;                        // 256
  float* combos = ss + 256;                      // 5*15*128 = 9600
  int* deg = (int*)(combos + 9600);              // NN (also reused as scatter cursor)
  int* off = deg + NN;                           // NN+1
  int* csr = off + NN + 1;                       // NE
  int* bsum = csr + NE;                          // 128

  const int NB_SCAN = (NN + 1023) / 1024;  // 98

  // ---- one-time per launch: CSR build + combo tables ----
  hipMemsetAsync(deg, 0, NN * sizeof(int), stream);
  hist_kernel<<<(NE + 255) / 256, 256, 0, stream>>>(ei, deg);
  scan1_kernel<<<NB_SCAN, 256, 0, stream>>>(deg, off, bsum);
  scan2_kernel<<<1, 64, 0, stream>>>(bsum, off, NB_SCAN);
  scan3_kernel<<<(NN + 255) / 256, 256, 0, stream>>>(off, bsum);
  hipMemsetAsync(deg, 0, NN * sizeof(int), stream);  // reuse as cursor
  scatter_kernel<<<(NE + 255) / 256, 256, 0, stream>>>(ei, ea, off, deg, csr);
  combo_kernel<<<(5 * 15 * 128 + 255) / 256, 256, 0, stream>>>(ee1, ee2, combos);

  node_init_kernel<<<(NN * 32 + 255) / 256, 256, 0, stream>>>(x, x_emb1, x_emb2, hbuf);

  for (int i = 0; i < 5; ++i) {
    hipMemsetAsync(sums, 0, 256 * sizeof(float), stream);

    gather_agg_kernel<<<(NN * 32 + 255) / 256, 256, 0, stream>>>(
        hbuf, off, csr, combos + (size_t)i * 15 * EMB, agg);

    dim3 g1(4, (NN + 63) / 64);
    gemm_kernel<128, 256, true, true><<<g1, 256, 0, stream>>>(
        hbuf, agg, eps + i, W1 + (size_t)i * 128 * 256, b1 + (size_t)i * 256, hmid);

    dim3 g2(2, (NN + 63) / 64);
    gemm_kernel<256, 128, false, false><<<g2, 256, 0, stream>>>(
        hmid, nullptr, nullptr, W2 + (size_t)i * 256 * 128, b2 + (size_t)i * 128,
        agg /* hpre aliases agg: agg already consumed by gemm1 */);

    bn_reduce_kernel<<<512, 256, 0, stream>>>(agg, sums);
    bn_stats_kernel<<<1, 128, 0, stream>>>(sums, gamma + (size_t)i * EMB,
                                           beta + (size_t)i * EMB, ss);
    if (i < 4)
      bn_apply_kernel<true><<<(NN * 32 + 255) / 256, 256, 0, stream>>>(agg, ss, hbuf);
    else
      bn_apply_kernel<false><<<(NN * 32 + 255) / 256, 256, 0, stream>>>(agg, ss, out);
  }
}

// Round 3
// 1081.474 us; speedup vs baseline: 6.8033x; 1.7006x over previous
//
#include <hip/hip_runtime.h>

#define NN 100000
#define NE 600000
#define EMB 128

typedef unsigned short u16;
typedef unsigned int u32;
typedef short short8 __attribute__((ext_vector_type(8)));
typedef float f32x4 __attribute__((ext_vector_type(4)));

__device__ __forceinline__ float4 ld4(const float* p) { return *(const float4*)p; }
__device__ __forceinline__ u16 f2bf(float x) {          // RTNE f32 -> bf16
  u32 u = __float_as_uint(x);
  u += 0x7FFFu + ((u >> 16) & 1u);
  return (u16)(u >> 16);
}
__device__ __forceinline__ float bf2f(u16 h) { return __uint_as_float(((u32)h) << 16); }
// As LDS slot swizzle (breaks staging-write bank collisions; bijective per 64-slot block)
__device__ __forceinline__ int aslot(int lane, int kt) {
  return lane ^ kt ^ (((lane >> 4) & 1) << 2);
}

// ---------------- node embedding init: hb(bf16) = emb1[x0] + emb2[x1] ----------------
__global__ __launch_bounds__(256) void node_init_kernel(
    const int* __restrict__ x, const float* __restrict__ emb1,
    const float* __restrict__ emb2, u16* __restrict__ hb) {
  int tid = blockIdx.x * blockDim.x + threadIdx.x;
  int n = tid >> 4;
  if (n >= NN) return;
  int kc = tid & 15;
  int x0 = min(max(x[2 * n], 0), 118);
  int x1 = min(max(x[2 * n + 1], 0), 2);  // x[:,1] sampled 0..118 -> clip to NUM_CHIR-1
  const float* p1 = emb1 + (size_t)x0 * EMB + kc * 8;
  const float* p2 = emb2 + (size_t)x1 * EMB + kc * 8;
  u16* d = hb + (size_t)n * EMB + kc * 8;
  u16 o[8];
#pragma unroll
  for (int j = 0; j < 8; ++j) o[j] = f2bf(p1[j] + p2[j]);
  *(ulonglong2*)d = *(ulonglong2*)o;
}

// ---------------- CSR build ----------------
__global__ __launch_bounds__(256) void hist_kernel(const int* __restrict__ ei,
                                                   int* __restrict__ deg) {
  int e = blockIdx.x * blockDim.x + threadIdx.x;
  if (e >= NE) return;
  atomicAdd(&deg[ei[NE + e]], 1);
}

__global__ __launch_bounds__(256) void scan1_kernel(const int* __restrict__ deg,
                                                    int* __restrict__ off,
                                                    int* __restrict__ bsum) {
  __shared__ int s[256];
  int t = threadIdx.x;
  int base = blockIdx.x * 1024 + t * 4;
  int v[4];
#pragma unroll
  for (int j = 0; j < 4; ++j) {
    int idx = base + j;
    v[j] = (idx < NN) ? deg[idx] : 0;
  }
  int tsum = v[0] + v[1] + v[2] + v[3];
  s[t] = tsum;
  __syncthreads();
  for (int d = 1; d < 256; d <<= 1) {
    int add = (t >= d) ? s[t - d] : 0;
    __syncthreads();
    s[t] += add;
    __syncthreads();
  }
  int run = s[t] - tsum;
#pragma unroll
  for (int j = 0; j < 4; ++j) {
    int idx = base + j;
    if (idx < NN) off[idx] = run;
    run += v[j];
  }
  if (t == 255) bsum[blockIdx.x] = s[255];
}

__global__ void scan2_kernel(int* __restrict__ bsum, int* __restrict__ off, int nb) {
  if (threadIdx.x == 0) {
    int run = 0;
    for (int b = 0; b < nb; ++b) {
      int v = bsum[b];
      bsum[b] = run;
      run += v;
    }
    off[NN] = run;
  }
}

__global__ __launch_bounds__(256) void scan3_kernel(int* __restrict__ off,
                                                    const int* __restrict__ bsum) {
  int idx = blockIdx.x * blockDim.x + threadIdx.x;
  if (idx < NN) off[idx] += bsum[idx >> 10];
}

__global__ __launch_bounds__(256) void scatter_kernel(
    const int* __restrict__ ei, const int* __restrict__ ea,
    const int* __restrict__ off, int* __restrict__ cnt, int* __restrict__ csr) {
  int e = blockIdx.x * blockDim.x + threadIdx.x;
  if (e >= NE) return;
  int d = ei[NE + e];
  int s = ei[e];
  int a0 = min(max(ea[2 * e], 0), 4);
  int a1 = min(max(ea[2 * e + 1], 0), 2);
  int code = a0 * 3 + a1;  // [0,14]
  int r = atomicAdd(&cnt[d], 1);
  csr[off[d] + r] = s | (code << 20);
}

// combos[l][code][f] = ee1[l][code/3][f] + ee2[l][code%3][f]
__global__ __launch_bounds__(256) void combo_kernel(const float* __restrict__ ee1,
                                                    const float* __restrict__ ee2,
                                                    float* __restrict__ combos) {
  int idx = blockIdx.x * blockDim.x + threadIdx.x;
  if (idx >= 5 * 15 * 128) return;
  int l = idx / (15 * 128);
  int rem = idx % (15 * 128);
  int code = rem / 128;
  int f = rem % 128;
  combos[idx] = ee1[(l * 5 + code / 3) * 128 + f] + ee2[(l * 3 + code % 3) * 128 + f];
}

// ---------------- weight prep: frag-ordered bf16 copies of W1/W2 (all 5 layers) ----------------
// W1f[l][c:4][kt:4][nt:4][lane:64][8]: lane=(n%16)+16*q holds W1[l][kt*32+q*8+j][c*64+nt*16+(n%16)]
// W2f[l][c:4][ktl:2][nt:8][lane:64][8]: holds W2[l][c*64+ktl*32+q*8+j][nt*16+(lane&15)]
__global__ __launch_bounds__(256) void prep_w_kernel(const float* __restrict__ W1g,
                                                     const float* __restrict__ W2g,
                                                     u16* __restrict__ W1f,
                                                     u16* __restrict__ W2f) {
  int idx = blockIdx.x * blockDim.x + threadIdx.x;
  if (idx >= 40960) return;
  u16 o[8];
  if (idx < 20480) {
    int lane = idx & 63;
    int r = idx >> 6;             // l*64 + c*16 + kt*4 + nt
    int nt = r & 3, kt = (r >> 2) & 3, c = (r >> 4) & 3, l = r >> 6;
    int n = c * 64 + nt * 16 + (lane & 15);
    int kb = kt * 32 + (lane >> 4) * 8;
#pragma unroll
    for (int j = 0; j < 8; ++j) o[j] = f2bf(W1g[((size_t)l * 128 + kb + j) * 256 + n]);
    *(ulonglong2*)(W1f + (size_t)idx * 8) = *(ulonglong2*)o;
  } else {
    int i2 = idx - 20480;
    int lane = i2 & 63;
    int r = i2 >> 6;              // l*64 + c*16 + ktl*8 + nt
    int nt = r & 7, ktl = (r >> 3) & 1, c = (r >> 4) & 3, l = r >> 6;
    int n = nt * 16 + (lane & 15);
    int kb = c * 64 + ktl * 32 + (lane >> 4) * 8;
#pragma unroll
    for (int j = 0; j < 8; ++j) o[j] = f2bf(W2g[((size_t)l * 256 + kb + j) * 128 + n]);
    *(ulonglong2*)(W2f + (size_t)i2 * 8) = *(ulonglong2*)o;
  }
}

// ---------------- fused layer: gather+combine -> MFMA MLP -> hpre + BN partials ----------------
// 128 rows/block, 256 threads (4 waves). LDS: As 32KB (A-frags), Hs 16KB (hmid frags).
__global__ __launch_bounds__(256) void fused_layer_kernel(
    const u16* __restrict__ hb, const int* __restrict__ off,
    const int* __restrict__ csr, const float* __restrict__ cb,
    const float* __restrict__ epsp, const u16* __restrict__ W1fl,
    const u16* __restrict__ W2fl, const float* __restrict__ b1g,
    const float* __restrict__ b2g, float* __restrict__ hpre,
    float* __restrict__ sums) {
  __shared__ __align__(16) u16 As[8 * 4 * 64 * 8];  // [mt][kt][slot][8]
  __shared__ __align__(16) u16 Hs[8 * 2 * 64 * 8];  // [mt][ktl][lane][8] (A-frag order)

  const int t = threadIdx.x;
  const int m0 = blockIdx.x * 128;
  const float eps1 = 1.0f + *epsp;

  // ---- phase 0: gather + combine -> A fragments (bf16) ----
  {
    const int a_r = t >> 4;   // row-in-tile 0..15
    const int kc = t & 15;    // 8-feat chunk
    const int kt = kc >> 2, kcm = kc & 3;
    const int lane_s = a_r + 16 * kcm;
    const int slot = aslot(lane_s, kt);
#pragma unroll 2
    for (int p = 0; p < 8; ++p) {
      int m = m0 + p * 16 + a_r;
      float av[8] = {0.f, 0.f, 0.f, 0.f, 0.f, 0.f, 0.f, 0.f};
      if (m < NN) {
        ulonglong2 hraw = *(const ulonglong2*)(hb + (size_t)m * EMB + kc * 8);
        u16* hr = (u16*)&hraw;
        float hv[8];
        float4 c0a = ld4(cb + kc * 8), c0b = ld4(cb + kc * 8 + 4);
        const float* c0 = (const float*)&c0a;  // careful: use arrays instead
        float cself[8] = {c0a.x, c0a.y, c0a.z, c0a.w, c0b.x, c0b.y, c0b.z, c0b.w};
        (void)c0;
#pragma unroll
        for (int j = 0; j < 8; ++j) {
          hv[j] = bf2f(hr[j]);
          av[j] = fmaxf(hv[j] + cself[j], 0.f);  // self loop, code 0
        }
        int s0 = off[m], s1 = off[m + 1];
        for (int e = s0; e < s1; ++e) {
          int pk = csr[e];
          int src = pk & 0xFFFFF;
          int code = pk >> 20;
          ulonglong2 sraw = *(const ulonglong2*)(hb + (size_t)src * EMB + kc * 8);
          u16* sr = (u16*)&sraw;
          const float* cv = cb + code * 128 + kc * 8;
          float4 cva = ld4(cv), cvb = ld4(cv + 4);
          float cc[8] = {cva.x, cva.y, cva.z, cva.w, cvb.x, cvb.y, cvb.z, cvb.w};
#pragma unroll
          for (int j = 0; j < 8; ++j) av[j] += fmaxf(bf2f(sr[j]) + cc[j], 0.f);
        }
#pragma unroll
        for (int j = 0; j < 8; ++j) av[j] += eps1 * hv[j];
      }
      u16 o[8];
#pragma unroll
      for (int j = 0; j < 8; ++j) o[j] = f2bf(av[j]);
      *(ulonglong2*)&As[(((size_t)p * 4 + kt) * 64 + slot) * 8] = *(ulonglong2*)o;
    }
  }

  const int w = t >> 6;
  const int lane = t & 63;
  const int quad = lane >> 4, l15 = lane & 15;
  const int wr = w >> 1, wc = w & 1;

  f32x4 oacc[4][4];
#pragma unroll
  for (int a = 0; a < 4; ++a)
#pragma unroll
    for (int b = 0; b < 4; ++b) oacc[a][b] = (f32x4){0.f, 0.f, 0.f, 0.f};

  // ---- chunk loop over hmid columns (4 x 64) ----
  for (int c = 0; c < 4; ++c) {
    __syncthreads();  // As ready (c=0) / Hs consumed (c>0)

    // stage 1: hmid[128][64c] = relu(A @ W1[:,c] + b1)   wave w -> rows 32w..32w+31
    f32x4 hacc[2][4];
#pragma unroll
    for (int a = 0; a < 2; ++a)
#pragma unroll
      for (int b = 0; b < 4; ++b) hacc[a][b] = (f32x4){0.f, 0.f, 0.f, 0.f};
#pragma unroll
    for (int kt = 0; kt < 4; ++kt) {
      int sl = aslot(lane, kt);
      short8 a0 = *(short8*)&As[(((2 * w) * 4 + kt) * 64 + sl) * 8];
      short8 a1 = *(short8*)&As[(((2 * w + 1) * 4 + kt) * 64 + sl) * 8];
#pragma unroll
      for (int nt = 0; nt < 4; ++nt) {
        short8 bf = *(const short8*)(W1fl + (((size_t)(c * 4 + kt) * 4 + nt) * 64 + lane) * 8);
        hacc[0][nt] = __builtin_amdgcn_mfma_f32_16x16x32_bf16(a0, bf, hacc[0][nt], 0, 0, 0);
        hacc[1][nt] = __builtin_amdgcn_mfma_f32_16x16x32_bf16(a1, bf, hacc[1][nt], 0, 0, 0);
      }
    }
    // epilogue: +b1, relu, scatter to Hs in A-frag order
#pragma unroll
    for (int nt = 0; nt < 4; ++nt) {
      float b1v = b1g[c * 64 + nt * 16 + l15];
      int lcol = nt * 16 + l15;
      int ktl = lcol >> 5;
      int qp = (lcol >> 3) & 3;
      int j = lcol & 7;
#pragma unroll
      for (int mi = 0; mi < 2; ++mi) {
        int mt = 2 * w + mi;
#pragma unroll
        for (int reg = 0; reg < 4; ++reg) {
          float v = fmaxf(hacc[mi][nt][reg] + b1v, 0.f);
          int lp = (quad * 4 + reg) + 16 * qp;
          Hs[(((size_t)mt * 2 + ktl) * 64 + lp) * 8 + j] = f2bf(v);
        }
      }
    }
    __syncthreads();

    // stage 2: out[128][128] += hmid_c @ W2[c,:]   wave (wr,wc) -> 64x64 quadrant
#pragma unroll
    for (int ktl = 0; ktl < 2; ++ktl) {
      short8 a2[4];
#pragma unroll
      for (int mi = 0; mi < 4; ++mi)
        a2[mi] = *(short8*)&Hs[(((size_t)(4 * wr + mi) * 2 + ktl) * 64 + lane) * 8];
#pragma unroll
      for (int nt = 0; nt < 4; ++nt) {
        short8 bf = *(const short8*)(W2fl + (((size_t)(c * 2 + ktl) * 8 + wc * 4 + nt) * 64 + lane) * 8);
#pragma unroll
        for (int mi = 0; mi < 4; ++mi)
          oacc[mi][nt] = __builtin_amdgcn_mfma_f32_16x16x32_bf16(a2[mi], bf, oacc[mi][nt], 0, 0, 0);
      }
    }
  }

  // ---- final epilogue: +b2, store hpre (f32), BN partial sums ----
#pragma unroll
  for (int nt = 0; nt < 4; ++nt) {
    int col = wc * 64 + nt * 16 + l15;
    float b2v = b2g[col];
    float s = 0.f, s2 = 0.f;
#pragma unroll
    for (int mi = 0; mi < 4; ++mi) {
      int rowb = m0 + (4 * wr + mi) * 16 + quad * 4;
#pragma unroll
      for (int reg = 0; reg < 4; ++reg) {
        int row = rowb + reg;
        float v = oacc[mi][nt][reg] + b2v;
        if (row < NN) {
          hpre[(size_t)row * EMB + col] = v;
          s += v;
          s2 += v * v;
        }
      }
    }
    s += __shfl_xor(s, 16);
    s += __shfl_xor(s, 32);
    s2 += __shfl_xor(s2, 16);
    s2 += __shfl_xor(s2, 32);
    if (quad == 0) {
      atomicAdd(&sums[col], s);
      atomicAdd(&sums[128 + col], s2);
    }
  }
}

// ---------------- BN stats + apply ----------------
__global__ void bn_stats_kernel(const float* __restrict__ sums,
                                const float* __restrict__ gamma,
                                const float* __restrict__ beta,
                                float* __restrict__ ss) {
  int f = threadIdx.x;  // 128
  float mean = sums[f] * (1.0f / NN);
  float var = sums[128 + f] * (1.0f / NN) - mean * mean;  // biased
  float sc = gamma[f] * rsqrtf(var + 1e-5f);
  ss[f] = sc;
  ss[128 + f] = beta[f] - mean * sc;
}

template <bool LAST>
__global__ __launch_bounds__(256) void bn_apply_kernel(
    const float* __restrict__ hp, const float* __restrict__ ss,
    u16* __restrict__ hb, float* __restrict__ out) {
  int tid = blockIdx.x * blockDim.x + threadIdx.x;
  int n = tid >> 4;
  if (n >= NN) return;
  int kc = tid & 15;
  const float* p = hp + (size_t)n * EMB + kc * 8;
  float4 va = ld4(p), vb = ld4(p + 4);
  float4 sa = ld4(ss + kc * 8), sb = ld4(ss + kc * 8 + 4);
  float4 ta = ld4(ss + 128 + kc * 8), tb = ld4(ss + 128 + kc * 8 + 4);
  float v[8] = {va.x * sa.x + ta.x, va.y * sa.y + ta.y, va.z * sa.z + ta.z,
                va.w * sa.w + ta.w, vb.x * sb.x + tb.x, vb.y * sb.y + tb.y,
                vb.z * sb.z + tb.z, vb.w * sb.w + tb.w};
  if (LAST) {
    float* d = out + (size_t)n * EMB + kc * 8;
    *(float4*)d = make_float4(v[0], v[1], v[2], v[3]);
    *(float4*)(d + 4) = make_float4(v[4], v[5], v[6], v[7]);
  } else {
    u16 o[8];
#pragma unroll
    for (int j = 0; j < 8; ++j) o[j] = f2bf(fmaxf(v[j], 0.f));
    *(ulonglong2*)(hb + (size_t)n * EMB + kc * 8) = *(ulonglong2*)o;
  }
}

// ---------------- launch ----------------
extern "C" void kernel_launch(void* const* d_in, const int* in_sizes, int n_in,
                              void* d_out, int out_size, void* d_ws, size_t ws_size,
                              hipStream_t stream) {
  const int* x = (const int*)d_in[0];
  const int* ei = (const int*)d_in[1];
  const int* ea = (const int*)d_in[2];
  const float* x_emb1 = (const float*)d_in[3];
  const float* x_emb2 = (const float*)d_in[4];
  const float* ee1 = (const float*)d_in[5];
  const float* ee2 = (const float*)d_in[6];
  const float* W1 = (const float*)d_in[7];
  const float* b1 = (const float*)d_in[8];
  const float* W2 = (const float*)d_in[9];
  const float* b2 = (const float*)d_in[10];
  const float* eps = (const float*)d_in[11];
  const float* gamma = (const float*)d_in[12];
  const float* beta = (const float*)d_in[13];
  float* out = (float*)d_out;

  // workspace layout (16B-aligned sections)
  float* hpre = (float*)d_ws;                 // NN*128 f32
  float* sums = hpre + (size_t)NN * EMB;      // 256
  float* ss = sums + 256;                     // 256
  float* combos = ss + 256;                   // 5*15*128 = 9600
  u16* hb = (u16*)(combos + 9600);            // NN*128 u16
  u16* W1f = hb + (size_t)NN * EMB;           // 5*32768
  u16* W2f = W1f + 5 * 32768;                 // 5*32768
  int* deg = (int*)(W2f + 5 * 32768);         // NN
  int* off = deg + NN;                        // NN+1
  int* csr = off + NN + 1;                    // NE
  int* bsum = csr + NE;                       // 128

  const int NB_SCAN = (NN + 1023) / 1024;

  // one-time per launch: CSR + combo tables + frag-ordered bf16 weights
  hipMemsetAsync(deg, 0, NN * sizeof(int), stream);
  hist_kernel<<<(NE + 255) / 256, 256, 0, stream>>>(ei, deg);
  scan1_kernel<<<NB_SCAN, 256, 0, stream>>>(deg, off, bsum);
  scan2_kernel<<<1, 64, 0, stream>>>(bsum, off, NB_SCAN);
  scan3_kernel<<<(NN + 255) / 256, 256, 0, stream>>>(off, bsum);
  hipMemsetAsync(deg, 0, NN * sizeof(int), stream);
  scatter_kernel<<<(NE + 255) / 256, 256, 0, stream>>>(ei, ea, off, deg, csr);
  combo_kernel<<<(5 * 15 * 128 + 255) / 256, 256, 0, stream>>>(ee1, ee2, combos);
  prep_w_kernel<<<160, 256, 0, stream>>>(W1, W2, W1f, W2f);
  node_init_kernel<<<(NN * 16 + 255) / 256, 256, 0, stream>>>(x, x_emb1, x_emb2, hb);

  const int NBLK = (NN + 127) / 128;  // 782
  for (int i = 0; i < 5; ++i) {
    hipMemsetAsync(sums, 0, 256 * sizeof(float), stream);
    fused_layer_kernel<<<NBLK, 256, 0, stream>>>(
        hb, off, csr, combos + (size_t)i * 15 * EMB, eps + i,
        W1f + (size_t)i * 32768, W2f + (size_t)i * 32768,
        b1 + (size_t)i * 256, b2 + (size_t)i * 128, hpre, sums);
    bn_stats_kernel<<<1, 128, 0, stream>>>(sums, gamma + (size_t)i * EMB,
                                           beta + (size_t)i * EMB, ss);
    if (i < 4)
      bn_apply_kernel<false><<<(NN * 16 + 255) / 256, 256, 0, stream>>>(hpre, ss, hb, nullptr);
    else
      bn_apply_kernel<true><<<(NN * 16 + 255) / 256, 256, 0, stream>>>(hpre, ss, nullptr, out);
  }
}